// Round 1
// baseline (452.001 us; speedup 1.0000x reference)
//
#include <hip/hip_runtime.h>
#include <hip/hip_bf16.h>
#include <cstdint>

#define TSEQ 2048
#define NB   2
#define NH   16
#define NKV  4
#define HD   128
#define EMB  2048
#define WIN  512

typedef unsigned short u16;
typedef __attribute__((ext_vector_type(8))) short s16x8;
typedef __attribute__((ext_vector_type(4))) float f32x4;
typedef __attribute__((ext_vector_type(4))) unsigned short u16x4;

__device__ __forceinline__ u16 f2bf(float x) {
    unsigned u = __builtin_bit_cast(unsigned, x);
    u += 0x7fffu + ((u >> 16) & 1u);
    return (u16)(u >> 16);
}
__device__ __forceinline__ float bf2f(u16 u) {
    return __builtin_bit_cast(float, ((unsigned)u) << 16);
}

__device__ __forceinline__ void gld_lds16(const void* g, void* l) {
    __builtin_amdgcn_global_load_lds(
        (__attribute__((address_space(1))) void*)(void*)(g),
        (__attribute__((address_space(3))) void*)(l),
        16, 0, 0);
}

__device__ __forceinline__ f32x4 mfma16(s16x8 a, s16x8 b, f32x4 c) {
    return __builtin_amdgcn_mfma_f32_16x16x32_bf16(a, b, c, 0, 0, 0);
}

// ---------------- fp32 -> bf16 cast (4 elems/thread) ----------------
__global__ void cast_kernel(const float* __restrict__ src, u16* __restrict__ dst, int n) {
    int i = (blockIdx.x * 256 + threadIdx.x) * 4;
    if (i >= n) return;
    float4 v = *(const float4*)(src + i);
    u16x4 o;
    o[0] = f2bf(v.x); o[1] = f2bf(v.y); o[2] = f2bf(v.z); o[3] = f2bf(v.w);
    *(u16x4*)(dst + i) = o;
}

// ---------------- m97-style bf16 GEMM:  C[M][N] = A[M][K] * B[N][K]^T ----------------
// 128x128 block tile, BK=32, 4 waves in 2x2 grid (64x64 each, 4x4 MFMA tiles of 16x16x32)
template <int BF16OUT>
__global__ __launch_bounds__(256) void gemm_bt(const u16* __restrict__ A, const u16* __restrict__ B,
                                               void* __restrict__ Cp, int M, int N, int K) {
    __shared__ __align__(16) u16 As[128 * 32];
    __shared__ __align__(16) u16 Bs[128 * 32];
    const int tid  = threadIdx.x;
    const int lane = tid & 63;
    const int w    = tid >> 6;
    const int l15  = lane & 15;
    const int quad = lane >> 4;
    const int wr   = w >> 1, wc = w & 1;

    // staging: each wave issues 2 A-rows-of-16 and 2 B-rows-of-16 per K-step.
    // global_load_lds: LDS dest = uniform base + lane*16; lane -> row = lane/4, colbyte = (lane&3)*16
    const int srow  = w * 32 + (lane >> 2);
    const int cbyte = (lane & 3) * 16;
    const char* ag0 = (const char*)(A + (size_t)(blockIdx.y * 128 + srow) * K) + cbyte;
    const char* ag1 = ag0 + (size_t)16 * K * 2;
    const char* bg0 = (const char*)(B + (size_t)(blockIdx.x * 128 + srow) * K) + cbyte;
    const char* bg1 = bg0 + (size_t)16 * K * 2;
    char* al0 = (char*)As + (w * 32) * 64;
    char* al1 = al0 + 16 * 64;
    char* bl0 = (char*)Bs + (w * 32) * 64;
    char* bl1 = bl0 + 16 * 64;

    f32x4 acc[4][4];
#pragma unroll
    for (int i = 0; i < 4; i++)
#pragma unroll
        for (int j = 0; j < 4; j++)
            acc[i][j] = f32x4{0.f, 0.f, 0.f, 0.f};

    for (int k0 = 0; k0 < K; k0 += 32) {
        gld_lds16(ag0, al0);
        gld_lds16(ag1, al1);
        gld_lds16(bg0, bl0);
        gld_lds16(bg1, bl1);
        ag0 += 64; ag1 += 64; bg0 += 64; bg1 += 64;
        __syncthreads();   // drains vmcnt (global_load_lds) + barrier
        s16x8 af[4], bf[4];
#pragma unroll
        for (int i = 0; i < 4; i++)
            af[i] = *(const s16x8*)(As + (wr * 64 + i * 16 + l15) * 32 + quad * 8);
#pragma unroll
        for (int j = 0; j < 4; j++)
            bf[j] = *(const s16x8*)(Bs + (wc * 64 + j * 16 + l15) * 32 + quad * 8);
#pragma unroll
        for (int i = 0; i < 4; i++)
#pragma unroll
            for (int j = 0; j < 4; j++)
                acc[i][j] = mfma16(af[i], bf[j], acc[i][j]);
        __syncthreads();   // protect LDS from next staging
    }

    const int row0 = blockIdx.y * 128 + wr * 64;
    const int col0 = blockIdx.x * 128 + wc * 64 + l15;
#pragma unroll
    for (int i = 0; i < 4; i++)
#pragma unroll
        for (int j = 0; j < 4; j++)
#pragma unroll
            for (int r = 0; r < 4; r++) {
                int row = row0 + i * 16 + quad * 4 + r;
                int col = col0 + j * 16;
                if (BF16OUT)
                    ((u16*)Cp)[(size_t)row * N + col] = f2bf(acc[i][j][r]);
                else
                    ((float*)Cp)[(size_t)row * N + col] = acc[i][j][r];
            }
}

// ---------------- RoPE in-place on bf16, thread per (row, head, d<64) ----------------
__global__ void rope_kernel(u16* __restrict__ buf, int rowstride, int heads, int n) {
    int i = blockIdx.x * 256 + threadIdx.x;
    if (i >= n) return;
    int d   = i & 63;
    int hh  = (i >> 6) % heads;
    int row = i / (64 * heads);
    int t   = row & (TSEQ - 1);
    size_t base = (size_t)row * rowstride + hh * HD + d;
    float x1 = bf2f(buf[base]);
    float x2 = bf2f(buf[base + 64]);
    // inv_freq = 10000^(-d/64) = exp(-d * ln(10000)/64)
    float inv = __expf(-(float)d * (9.210340371976184f / 64.0f));
    float ang = (float)t * inv;
    float s, c;
    sincosf(ang, &s, &c);
    buf[base]      = f2bf(x1 * c - x2 * s);
    buf[base + 64] = f2bf(x2 * c + x1 * s);
}

// ---------------- V transpose: kvb[b][t][512 + kv*128 + d] -> vt[b][kv][d][t] ----------------
__global__ void transpose_v(const u16* __restrict__ kvb, u16* __restrict__ vt, int n) {
    int o = blockIdx.x * 256 + threadIdx.x;
    if (o >= n) return;
    int t    = o & (TSEQ - 1);
    int rest = o >> 11;
    int d    = rest & (HD - 1);
    int kvi  = (rest >> 7) & (NKV - 1);
    int b    = rest >> 9;
    vt[o] = kvb[(size_t)(b * TSEQ + t) * 1024 + 512 + kvi * HD + d];
}

// ---------------- flash attention, 1 wave per 16-query tile, 32-key blocks ----------------
__global__ __launch_bounds__(256) void attn_kernel(const u16* __restrict__ qb, const u16* __restrict__ kvb,
                                                   const u16* __restrict__ vt, u16* __restrict__ ao) {
    __shared__ __align__(16) u16 Pl[4 * 512];   // per-wave 16x32 bf16 P tile
    const int lane = threadIdx.x & 63;
    const int w    = threadIdx.x >> 6;
    const int l15  = lane & 15;
    const int quad = lane >> 4;
    const int qt   = blockIdx.x * 4 + w;
    const int h    = blockIdx.y;
    const int b    = blockIdx.z;
    const int q0   = qt * 16;
    const int kv   = h >> 2;                    // N_REP = 4
    const float scale = 0.08838834764831845f;   // 1/sqrt(128)

    // Q fragments (A-operand): m = l15, k = quad*8 + j, 4 chunks of K=32
    s16x8 aq[4];
    {
        const u16* qrow = qb + (size_t)(b * TSEQ + q0 + l15) * EMB + h * HD + quad * 8;
#pragma unroll
        for (int c = 0; c < 4; c++)
            aq[c] = *(const s16x8*)(qrow + c * 32);
    }

    f32x4 o[8];
#pragma unroll
    for (int n = 0; n < 8; n++) o[n] = f32x4{0.f, 0.f, 0.f, 0.f};
    float mrow[4] = {-1e30f, -1e30f, -1e30f, -1e30f};
    float lrow[4] = {0.f, 0.f, 0.f, 0.f};
    u16* Pw = Pl + w * 512;

    int kb0 = q0 - (WIN - 1);
    if (kb0 < 0) kb0 = 0;
    kb0 &= ~31;
    for (int kb = kb0; kb <= q0 + 15; kb += 32) {
        // scores S[16 q][32 k]: two 16x16 col tiles, 4 K-chunks each
        f32x4 s0 = f32x4{0.f, 0.f, 0.f, 0.f};
        f32x4 s1 = f32x4{0.f, 0.f, 0.f, 0.f};
        const u16* kr0 = kvb + (size_t)(b * TSEQ + kb + l15) * 1024 + kv * HD + quad * 8;
#pragma unroll
        for (int c = 0; c < 4; c++) {
            s16x8 bk0 = *(const s16x8*)(kr0 + c * 32);
            s16x8 bk1 = *(const s16x8*)(kr0 + 16 * 1024 + c * 32);
            s0 = mfma16(aq[c], bk0, s0);
            s1 = mfma16(aq[c], bk1, s1);
        }
        // online softmax; C-layout: row = quad*4 + r, col = l15 (+16 for tile 1)
        float p0[4], p1[4], alpha[4];
#pragma unroll
        for (int r = 0; r < 4; r++) {
            int row = q0 + quad * 4 + r;
            int c0  = kb + l15;
            int c1  = c0 + 16;
            float v0 = (c0 <= row && row - c0 < WIN) ? s0[r] * scale : -1e30f;
            float v1 = (c1 <= row && row - c1 < WIN) ? s1[r] * scale : -1e30f;
            float mx = fmaxf(v0, v1);
            mx = fmaxf(mx, __shfl_xor(mx, 1, 16));
            mx = fmaxf(mx, __shfl_xor(mx, 2, 16));
            mx = fmaxf(mx, __shfl_xor(mx, 4, 16));
            mx = fmaxf(mx, __shfl_xor(mx, 8, 16));
            float mnew = fmaxf(mrow[r], mx);
            float a  = __expf(mrow[r] - mnew);
            float e0 = __expf(v0 - mnew);
            float e1 = __expf(v1 - mnew);
            float rs = e0 + e1;
            rs += __shfl_xor(rs, 1, 16);
            rs += __shfl_xor(rs, 2, 16);
            rs += __shfl_xor(rs, 4, 16);
            rs += __shfl_xor(rs, 8, 16);
            lrow[r] = lrow[r] * a + rs;
            mrow[r] = mnew;
            alpha[r] = a;
            p0[r] = e0; p1[r] = e1;
        }
#pragma unroll
        for (int n = 0; n < 8; n++) {
            o[n][0] *= alpha[0]; o[n][1] *= alpha[1];
            o[n][2] *= alpha[2]; o[n][3] *= alpha[3];
        }
        // P: C-layout -> LDS -> A-layout (m120 pattern, per-wave, no barrier needed)
#pragma unroll
        for (int r = 0; r < 4; r++) {
            Pw[(quad * 4 + r) * 32 + l15]      = f2bf(p0[r]);
            Pw[(quad * 4 + r) * 32 + l15 + 16] = f2bf(p1[r]);
        }
        asm volatile("s_waitcnt lgkmcnt(0)" ::: "memory");
        s16x8 ap = *(const s16x8*)(Pw + l15 * 32 + quad * 8);
        // PV: B-operand from V^T (contiguous along keys), 8 dim tiles of 16
        const u16* vb0 = vt + ((size_t)(b * NKV + kv) * HD + l15) * TSEQ + kb + quad * 8;
#pragma unroll
        for (int n = 0; n < 8; n++) {
            s16x8 bv = *(const s16x8*)(vb0 + (size_t)n * 16 * TSEQ);
            o[n] = mfma16(ap, bv, o[n]);
        }
    }
    // epilogue: divide by l, write bf16 attn-out in (b,t,h,d)
#pragma unroll
    for (int n = 0; n < 8; n++)
#pragma unroll
        for (int r = 0; r < 4; r++) {
            float val = o[n][r] / lrow[r];
            ao[(size_t)(b * TSEQ + q0 + quad * 4 + r) * EMB + h * HD + n * 16 + l15] = f2bf(val);
        }
}

extern "C" void kernel_launch(void* const* d_in, const int* in_sizes, int n_in,
                              void* d_out, int out_size, void* d_ws, size_t ws_size,
                              hipStream_t stream) {
    const float* x  = (const float*)d_in[0];
    const float* Wq = (const float*)d_in[1];
    const float* Wk = (const float*)d_in[2];
    const float* Wv = (const float*)d_in[3];
    const float* Wo = (const float*)d_in[4];
    float* out = (float*)d_out;

    u16* ws   = (u16*)d_ws;
    u16* xb   = ws;               // 8388608  (4096 x 2048)   [reused as ao after GEMMs]
    u16* wqb  = xb + 8388608;     // 4194304  (2048 x 2048)
    u16* wkvb = wqb + 4194304;    // 2097152  (1024 x 2048)   rows 0..511 = Wk, 512..1023 = Wv
    u16* wob  = wkvb + 2097152;   // 4194304  (2048 x 2048)
    u16* qb   = wob + 4194304;    // 8388608  (4096 x 2048)   (b,t,h,d)
    u16* kvb  = qb + 8388608;     // 4194304  (4096 x 1024)   cols: [k(4x128) | v(4x128)]
    u16* vt   = kvb + 4194304;    // 2097152  (b,kv,d,t)
    u16* ao   = xb;               // alias: x_bf16 dead after the KV GEMM
    // total ws: 33,554,432 u16 = 64 MB

    // casts
    cast_kernel<<<8192, 256, 0, stream>>>(x,  xb,   8388608);
    cast_kernel<<<4096, 256, 0, stream>>>(Wq, wqb,  4194304);
    cast_kernel<<<1024, 256, 0, stream>>>(Wk, wkvb, 1048576);
    cast_kernel<<<1024, 256, 0, stream>>>(Wv, wkvb + 1048576, 1048576);
    cast_kernel<<<4096, 256, 0, stream>>>(Wo, wob,  4194304);

    // projections
    gemm_bt<1><<<dim3(16, 32), 256, 0, stream>>>(xb, wqb,  qb,  4096, 2048, 2048);
    gemm_bt<1><<<dim3(8, 32),  256, 0, stream>>>(xb, wkvb, kvb, 4096, 1024, 2048);

    // rope (q: 16 heads, stride 2048; k: 4 heads, stride 1024 — v untouched)
    rope_kernel<<<16384, 256, 0, stream>>>(qb,  2048, 16, 4194304);
    rope_kernel<<<4096,  256, 0, stream>>>(kvb, 1024, 4,  1048576);

    // V^T for the PV MFMA B-operand
    transpose_v<<<8192, 256, 0, stream>>>(kvb, vt, 2097152);

    // windowed flash attention
    attn_kernel<<<dim3(32, 16, 2), 256, 0, stream>>>(qb, kvb, vt, ao);

    // output projection (fp32 out)
    gemm_bt<0><<<dim3(16, 32), 256, 0, stream>>>(ao, wob, out, 4096, 2048, 2048);
}

// Round 2
// 410.614 us; speedup vs baseline: 1.1008x; 1.1008x over previous
//
#include <hip/hip_runtime.h>
#include <hip/hip_bf16.h>
#include <cstdint>

#define TSEQ 2048
#define NB   2
#define NH   16
#define NKV  4
#define HD   128
#define EMB  2048
#define WIN  512

typedef unsigned short u16;
typedef __attribute__((ext_vector_type(8))) short s16x8;
typedef __attribute__((ext_vector_type(4))) float f32x4;
typedef __attribute__((ext_vector_type(4))) unsigned short u16x4;

__device__ __forceinline__ u16 f2bf(float x) {
    unsigned u = __builtin_bit_cast(unsigned, x);
    u += 0x7fffu + ((u >> 16) & 1u);
    return (u16)(u >> 16);
}
__device__ __forceinline__ float bf2f(u16 u) {
    return __builtin_bit_cast(float, ((unsigned)u) << 16);
}

__device__ __forceinline__ void gld_lds16(const void* g, void* l) {
    __builtin_amdgcn_global_load_lds(
        (__attribute__((address_space(1))) void*)(void*)(g),
        (__attribute__((address_space(3))) void*)(l),
        16, 0, 0);
}

__device__ __forceinline__ f32x4 mfma16(s16x8 a, s16x8 b, f32x4 c) {
    return __builtin_amdgcn_mfma_f32_16x16x32_bf16(a, b, c, 0, 0, 0);
}

// ---- DPP 16-lane reductions (VALU speed, no LDS pipe) ----
// quad_perm xor1 = 0xB1, xor2 = 0x4E; row_ror:8 = 0x128, row_ror:4 = 0x124
template <int CTRL>
__device__ __forceinline__ float dpp_movf(float x) {
    return __builtin_bit_cast(float,
        __builtin_amdgcn_update_dpp(0, __builtin_bit_cast(int, x), CTRL, 0xF, 0xF, true));
}
__device__ __forceinline__ float dpp_max16(float x) {
    x = fmaxf(x, dpp_movf<0xB1>(x));
    x = fmaxf(x, dpp_movf<0x4E>(x));
    x = fmaxf(x, dpp_movf<0x128>(x));
    x = fmaxf(x, dpp_movf<0x124>(x));
    return x;
}
__device__ __forceinline__ float dpp_sum16(float x) {
    x += dpp_movf<0xB1>(x);
    x += dpp_movf<0x4E>(x);
    x += dpp_movf<0x128>(x);
    x += dpp_movf<0x124>(x);
    return x;
}

// ---------------- fused fp32 -> bf16 casts (one kernel, 4 elems/thread) ----------------
__global__ void cast_all(const float* __restrict__ x,  const float* __restrict__ wq,
                         const float* __restrict__ wk, const float* __restrict__ wv,
                         const float* __restrict__ wo,
                         u16* __restrict__ xb, u16* __restrict__ wqb,
                         u16* __restrict__ wkvb, u16* __restrict__ wob) {
    long i = ((long)blockIdx.x * 256 + threadIdx.x) * 4;
    const float* s; u16* d; long off;
    if (i < 8388608L)        { s = x;  d = xb;             off = i; }
    else if (i < 12582912L)  { s = wq; d = wqb;            off = i - 8388608L; }
    else if (i < 13631488L)  { s = wk; d = wkvb;           off = i - 12582912L; }
    else if (i < 14680064L)  { s = wv; d = wkvb + 1048576; off = i - 13631488L; }
    else                     { s = wo; d = wob;            off = i - 14680064L; }
    float4 v = *(const float4*)(s + off);
    u16x4 o;
    o[0] = f2bf(v.x); o[1] = f2bf(v.y); o[2] = f2bf(v.z); o[3] = f2bf(v.w);
    *(u16x4*)(d + off) = o;
}

// ---------------- m97-style bf16 GEMM:  C[M][N] = A[M][K] * B[N][K]^T ----------------
// MODE 0: fp32 out (stride N). MODE 1: bf16 out (stride N).
// MODE 2: KV fused — cols<512 (K heads) -> bf16 at stride 512; cols>=512 (V) -> vt[b][kv][d][t]
template <int MODE>
__global__ __launch_bounds__(256) void gemm_bt(const u16* __restrict__ A, const u16* __restrict__ B,
                                               void* __restrict__ Cp, u16* __restrict__ vtp,
                                               int M, int N, int K) {
    __shared__ __align__(16) u16 As[128 * 32];
    __shared__ __align__(16) u16 Bs[128 * 32];
    const int tid  = threadIdx.x;
    const int lane = tid & 63;
    const int w    = tid >> 6;
    const int l15  = lane & 15;
    const int quad = lane >> 4;
    const int wr   = w >> 1, wc = w & 1;

    const int srow  = w * 32 + (lane >> 2);
    const int cbyte = (lane & 3) * 16;
    const char* ag0 = (const char*)(A + (size_t)(blockIdx.y * 128 + srow) * K) + cbyte;
    const char* ag1 = ag0 + (size_t)16 * K * 2;
    const char* bg0 = (const char*)(B + (size_t)(blockIdx.x * 128 + srow) * K) + cbyte;
    const char* bg1 = bg0 + (size_t)16 * K * 2;
    char* al0 = (char*)As + (w * 32) * 64;
    char* al1 = al0 + 16 * 64;
    char* bl0 = (char*)Bs + (w * 32) * 64;
    char* bl1 = bl0 + 16 * 64;

    f32x4 acc[4][4];
#pragma unroll
    for (int i = 0; i < 4; i++)
#pragma unroll
        for (int j = 0; j < 4; j++)
            acc[i][j] = f32x4{0.f, 0.f, 0.f, 0.f};

    for (int k0 = 0; k0 < K; k0 += 32) {
        gld_lds16(ag0, al0);
        gld_lds16(ag1, al1);
        gld_lds16(bg0, bl0);
        gld_lds16(bg1, bl1);
        ag0 += 64; ag1 += 64; bg0 += 64; bg1 += 64;
        __syncthreads();
        s16x8 af[4], bf[4];
#pragma unroll
        for (int i = 0; i < 4; i++)
            af[i] = *(const s16x8*)(As + (wr * 64 + i * 16 + l15) * 32 + quad * 8);
#pragma unroll
        for (int j = 0; j < 4; j++)
            bf[j] = *(const s16x8*)(Bs + (wc * 64 + j * 16 + l15) * 32 + quad * 8);
#pragma unroll
        for (int i = 0; i < 4; i++)
#pragma unroll
            for (int j = 0; j < 4; j++)
                acc[i][j] = mfma16(af[i], bf[j], acc[i][j]);
        __syncthreads();
    }

    const int row0 = blockIdx.y * 128 + wr * 64;
    const int col0 = blockIdx.x * 128 + wc * 64 + l15;
#pragma unroll
    for (int i = 0; i < 4; i++) {
        const int trow0 = row0 + i * 16 + quad * 4;
#pragma unroll
        for (int j = 0; j < 4; j++) {
            const int col = col0 + j * 16;
            if (MODE == 0) {
#pragma unroll
                for (int r = 0; r < 4; r++)
                    ((float*)Cp)[(size_t)(trow0 + r) * N + col] = acc[i][j][r];
            } else if (MODE == 1) {
#pragma unroll
                for (int r = 0; r < 4; r++)
                    ((u16*)Cp)[(size_t)(trow0 + r) * N + col] = f2bf(acc[i][j][r]);
            } else {
                if (col < 512) {
#pragma unroll
                    for (int r = 0; r < 4; r++)
                        ((u16*)Cp)[(size_t)(trow0 + r) * 512 + col] = f2bf(acc[i][j][r]);
                } else {
                    const int bb  = trow0 >> 11;
                    const int t0  = trow0 & (TSEQ - 1);
                    const int kvi = (col - 512) >> 7;
                    const int d   = (col - 512) & (HD - 1);
                    u16x4 pk;
#pragma unroll
                    for (int r = 0; r < 4; r++) pk[r] = f2bf(acc[i][j][r]);
                    *(u16x4*)(vtp + ((size_t)((bb * NKV + kvi) * HD + d)) * TSEQ + t0) = pk;
                }
            }
        }
    }
}

// ---------------- RoPE in-place on bf16 K (thread per (row, head, d<64)) ----------------
__global__ void rope_kernel(u16* __restrict__ buf, int rowstride, int heads, int n) {
    int i = blockIdx.x * 256 + threadIdx.x;
    if (i >= n) return;
    int d   = i & 63;
    int hh  = (i >> 6) % heads;
    int row = (i >> 6) / heads;
    int t   = row & (TSEQ - 1);
    size_t base = (size_t)row * rowstride + hh * HD + d;
    float x1 = bf2f(buf[base]);
    float x2 = bf2f(buf[base + 64]);
    float inv = __expf(-(float)d * (9.210340371976184f / 64.0f));
    float s, c;
    sincosf((float)t * inv, &s, &c);
    buf[base]      = f2bf(x1 * c - x2 * s);
    buf[base + 64] = f2bf(x2 * c + x1 * s);
}

// ---------------- flash attention, 1 wave per 16-query tile, 64-key blocks ----------------
__global__ __launch_bounds__(256) void attn_kernel(const u16* __restrict__ qb, const u16* __restrict__ kb,
                                                   const u16* __restrict__ vt, u16* __restrict__ ao) {
    __shared__ __align__(16) u16 Pl[4 * 1024];   // per-wave two 16x32 P half-tiles (stride 32)
    const int lane = threadIdx.x & 63;
    const int w    = threadIdx.x >> 6;
    const int l15  = lane & 15;
    const int quad = lane >> 4;
    const int qt   = blockIdx.x * 4 + w;
    const int h    = blockIdx.y;
    const int b    = blockIdx.z;
    const int q0   = qt * 16;
    const int kv   = h >> 2;                    // N_REP = 4
    const float scale = 0.08838834764831845f;   // 1/sqrt(128)

    // Q fragments (A-operand) with fused in-register RoPE (fp32, no bf16 roundtrip)
    s16x8 aq[4];
    {
        const u16* qrow = qb + (size_t)(b * TSEQ + q0 + l15) * EMB + h * HD + quad * 8;
        float qf[4][8];
#pragma unroll
        for (int c = 0; c < 4; c++)
#pragma unroll
            for (int e = 0; e < 8; e++)
                qf[c][e] = bf2f(qrow[c * 32 + e]);
        const int t = q0 + l15;
#pragma unroll
        for (int c = 0; c < 2; c++)
#pragma unroll
            for (int e = 0; e < 8; e++) {
                int f = quad * 8 + c * 32 + e;
                float inv = __expf(-(float)f * (9.210340371976184f / 64.0f));
                float s, cc;
                sincosf((float)t * inv, &s, &cc);
                float x1 = qf[c][e], x2 = qf[c + 2][e];
                qf[c][e]     = x1 * cc - x2 * s;
                qf[c + 2][e] = x2 * cc + x1 * s;
            }
#pragma unroll
        for (int c = 0; c < 4; c++)
#pragma unroll
            for (int e = 0; e < 8; e++)
                aq[c][e] = (short)f2bf(qf[c][e]);
    }

    f32x4 o[8];
#pragma unroll
    for (int n = 0; n < 8; n++) o[n] = f32x4{0.f, 0.f, 0.f, 0.f};
    float mrow[4] = {-1e30f, -1e30f, -1e30f, -1e30f};
    float lrow[4] = {0.f, 0.f, 0.f, 0.f};
    u16* Pw = Pl + w * 1024;

    int kb0 = q0 - (WIN - 1);
    if (kb0 < 0) kb0 = 0;
    kb0 &= ~63;
    for (int kbi = kb0; kbi <= q0 + 15; kbi += 64) {
        // ---- QK^T: 4 col tiles of 16 keys, 4 K-chunks each ----
        const u16* kr = kb + (size_t)(b * TSEQ + kbi + l15) * 512 + kv * HD + quad * 8;
        s16x8 bkf[4][4];
#pragma unroll
        for (int kt = 0; kt < 4; kt++)
#pragma unroll
            for (int c = 0; c < 4; c++)
                bkf[kt][c] = *(const s16x8*)(kr + kt * 16 * 512 + c * 32);
        f32x4 s[4];
#pragma unroll
        for (int kt = 0; kt < 4; kt++) s[kt] = f32x4{0.f, 0.f, 0.f, 0.f};
#pragma unroll
        for (int c = 0; c < 4; c++)
#pragma unroll
            for (int kt = 0; kt < 4; kt++)
                s[kt] = mfma16(aq[c], bkf[kt][c], s[kt]);

        // ---- V chunk-0 prefetch: latency covered by softmax ----
        const u16* vb = vt + ((size_t)(b * NKV + kv) * HD + l15) * TSEQ + kbi + quad * 8;
        s16x8 vf0[8];
#pragma unroll
        for (int n = 0; n < 8; n++)
            vf0[n] = *(const s16x8*)(vb + (size_t)n * 16 * TSEQ);

        // ---- online softmax (DPP reductions) ----
        float alpha[4], p[4][4];
#pragma unroll
        for (int r = 0; r < 4; r++) {
            const int row = q0 + quad * 4 + r;
            float v[4];
#pragma unroll
            for (int kt = 0; kt < 4; kt++) {
                int cidx = kbi + kt * 16 + l15;
                v[kt] = (cidx <= row && row - cidx < WIN) ? s[kt][r] * scale : -1e30f;
            }
            float mx = fmaxf(fmaxf(v[0], v[1]), fmaxf(v[2], v[3]));
            mx = dpp_max16(mx);
            float mnew = fmaxf(mrow[r], mx);
            alpha[r] = __expf(mrow[r] - mnew);
            float e0 = __expf(v[0] - mnew);
            float e1 = __expf(v[1] - mnew);
            float e2 = __expf(v[2] - mnew);
            float e3 = __expf(v[3] - mnew);
            float rs = (e0 + e1) + (e2 + e3);
            rs = dpp_sum16(rs);
            lrow[r] = lrow[r] * alpha[r] + rs;
            mrow[r] = mnew;
            p[0][r] = e0; p[1][r] = e1; p[2][r] = e2; p[3][r] = e3;
        }
#pragma unroll
        for (int n = 0; n < 8; n++) {
            o[n][0] *= alpha[0]; o[n][1] *= alpha[1];
            o[n][2] *= alpha[2]; o[n][3] *= alpha[3];
        }

        // ---- P: C-layout -> LDS -> A-layout (two 16x32 half-tiles, stride 32) ----
#pragma unroll
        for (int r = 0; r < 4; r++)
#pragma unroll
            for (int kt = 0; kt < 4; kt++)
                Pw[(kt >> 1) * 512 + (quad * 4 + r) * 32 + (kt & 1) * 16 + l15] = f2bf(p[kt][r]);
        asm volatile("s_waitcnt lgkmcnt(0)" ::: "memory");
        s16x8 ap0 = *(const s16x8*)(Pw + l15 * 32 + quad * 8);
        s16x8 ap1 = *(const s16x8*)(Pw + 512 + l15 * 32 + quad * 8);

        // ---- PV: chunk 0 from prefetched frags, chunk 1 inline ----
#pragma unroll
        for (int n = 0; n < 8; n++)
            o[n] = mfma16(ap0, vf0[n], o[n]);
#pragma unroll
        for (int n = 0; n < 8; n++) {
            s16x8 bv = *(const s16x8*)(vb + 32 + (size_t)n * 16 * TSEQ);
            o[n] = mfma16(ap1, bv, o[n]);
        }
    }

    // epilogue: divide by l, write bf16 attn-out in (b,t,h,d)
#pragma unroll
    for (int n = 0; n < 8; n++)
#pragma unroll
        for (int r = 0; r < 4; r++) {
            float val = o[n][r] / lrow[r];
            ao[(size_t)(b * TSEQ + q0 + quad * 4 + r) * EMB + h * HD + n * 16 + l15] = f2bf(val);
        }
}

extern "C" void kernel_launch(void* const* d_in, const int* in_sizes, int n_in,
                              void* d_out, int out_size, void* d_ws, size_t ws_size,
                              hipStream_t stream) {
    const float* x  = (const float*)d_in[0];
    const float* Wq = (const float*)d_in[1];
    const float* Wk = (const float*)d_in[2];
    const float* Wv = (const float*)d_in[3];
    const float* Wo = (const float*)d_in[4];
    float* out = (float*)d_out;

    u16* ws   = (u16*)d_ws;
    u16* xb   = ws;                 //  8388608  (4096 x 2048)  [reused as ao]
    u16* wqb  = ws + 8388608L;      //  4194304  (2048 x 2048)
    u16* wkvb = ws + 12582912L;     //  2097152  (1024 x 2048)  rows: Wk then Wv
    u16* wob  = ws + 14680064L;     //  4194304  (2048 x 2048)
    u16* qb   = ws + 18874368L;     //  8388608  (4096 x 2048)  raw Q (rope fused in attn)
    u16* kbuf = ws + 27262976L;     //  2097152  (4096 x 512)   roped K
    u16* vt   = ws + 29360128L;     //  2097152  (b,kv,d,t)     written by KV-GEMM epilogue
    u16* ao   = xb;                 // alias: x_bf16 dead after KV GEMM
    // total ws: 31,457,280 u16 = 60 MB

    cast_all<<<18432, 256, 0, stream>>>(x, Wq, Wk, Wv, Wo, xb, wqb, wkvb, wob);

    gemm_bt<1><<<dim3(16, 32), 256, 0, stream>>>(xb, wqb, qb, nullptr, 4096, 2048, 2048);
    gemm_bt<2><<<dim3(8, 32),  256, 0, stream>>>(xb, wkvb, kbuf, vt, 4096, 1024, 2048);

    rope_kernel<<<4096, 256, 0, stream>>>(kbuf, 512, 4, 1048576);

    attn_kernel<<<dim3(32, 16, 2), 256, 0, stream>>>(qb, kbuf, vt, ao);

    gemm_bt<0><<<dim3(16, 32), 256, 0, stream>>>(ao, wob, out, nullptr, 4096, 2048, 2048);
}